// Round 4
// baseline (587.826 us; speedup 1.0000x reference)
//
#include <hip/hip_runtime.h>

// Problem constants: x [32,64,64,64] f32, embed [64,512] f32.
#define N_VEC 131072       // 32*64*64 vectors
#define D 64               // embedding dim
#define K 512              // number of codes
#define NBLK (N_VEC / 128) // 1024 main blocks (128 queries per block)

// ---------------------------------------------------------------------------
// Prep: transpose embed [d][k] -> et [k][d] (contiguous code rows for the
// scalar-load path) and per-code norms (fma chain over d ascending — same
// order as rounds 1-3 so score numerics stay bit-identical).
// ---------------------------------------------------------------------------
__global__ __launch_bounds__(64) void vq_prep_kernel(
    const float* __restrict__ embed, float* __restrict__ et,
    float* __restrict__ nrm)
{
  const int k = blockIdx.x * 64 + threadIdx.x;  // grid = 8 x 64
  float s = 0.f;
#pragma unroll
  for (int d = 0; d < D; ++d) {
    const float e = embed[d * K + k];
    et[k * D + d] = e;
    s = fmaf(e, e, s);
  }
  nrm[k] = s;
}

// ---------------------------------------------------------------------------
// Main kernel: lane = query. xv[64] lives in VGPRs (static indexing only).
// Codebook rows are read at wave-uniform addresses -> scalar s_load + SGPR
// operand in v_fma; inner loop is a pure FMA stream (no LDS, no VMEM).
// Wave pairs split the codebook (half 0: k<256, half 1: k>=256); halves
// merge via LDS with first-min tie-break (A wins ties -> lower index), which
// is exact ordering logic — per-code scores are bit-identical to round 2.
// Epilogue fuses id write, q gather (L2-hot codebook), and diff partials.
// ---------------------------------------------------------------------------
__global__ __launch_bounds__(256, 4) void vq_main_kernel(
    const float* __restrict__ x, const float* __restrict__ et,
    const float* __restrict__ nrm, float* __restrict__ q,
    float* __restrict__ idf, float* __restrict__ partial)
{
  const int tid  = threadIdx.x;
  const int lane = tid & 63;
  const int wv   = tid >> 6;      // 0..3
  const int tile = wv >> 1;       // which 64-query tile of this block
  const int half = wv & 1;        // 0: codes 0-255, 1: codes 256-511
  const int myq  = blockIdx.x * 128 + tile * 64 + lane;

  // Load this lane's query row into registers (L1 merges the 256B-row reads).
  float xv[D];
  {
    const float4* xr = reinterpret_cast<const float4*>(x + (size_t)myq * D);
#pragma unroll
    for (int j = 0; j < D / 4; ++j) {
      const float4 t = xr[j];
      xv[4 * j + 0] = t.x; xv[4 * j + 1] = t.y;
      xv[4 * j + 2] = t.z; xv[4 * j + 3] = t.w;
    }
  }

  float best = 3.4e38f;
  int bid = 0;
  const int kbase = half * 256;

#pragma unroll 1   // keep code-group loop rolled; body ~300 instr
  for (int kc = 0; kc < 256; kc += 4) {
    const float* __restrict__ er = et + (size_t)(kbase + kc) * D;
    float a0 = 0.f, a1 = 0.f, a2 = 0.f, a3 = 0.f;
#pragma unroll
    for (int d = 0; d < D; ++d) {     // single fma chain per code, d ascending
      const float xd = xv[d];
      a0 = fmaf(xd, er[d], a0);
      a1 = fmaf(xd, er[D + d], a1);
      a2 = fmaf(xd, er[2 * D + d], a2);
      a3 = fmaf(xd, er[3 * D + d], a3);
    }
    const int k0 = kbase + kc;
    float s;
    s = fmaf(-2.f, a0, nrm[k0 + 0]); if (s < best) { best = s; bid = k0 + 0; }
    s = fmaf(-2.f, a1, nrm[k0 + 1]); if (s < best) { best = s; bid = k0 + 1; }
    s = fmaf(-2.f, a2, nrm[k0 + 2]); if (s < best) { best = s; bid = k0 + 2; }
    s = fmaf(-2.f, a3, nrm[k0 + 3]); if (s < best) { best = s; bid = k0 + 3; }
  }

  // Merge the two code-halves per query (ties -> half A = lower index).
  __shared__ float sbest[4][64];
  __shared__ int   sbid[4][64];
  __shared__ float sd[4];
  sbest[wv][lane] = best;
  sbid[wv][lane]  = bid;
  __syncthreads();
  const float sA = sbest[tile * 2 + 0][lane];
  const int   bA = sbid [tile * 2 + 0][lane];
  const float sB = sbest[tile * 2 + 1][lane];
  const int   bB = sbid [tile * 2 + 1][lane];
  const int id = (sB < sA) ? bB : bA;
  if (half == 0) idf[myq] = (float)id;

  // Fused gather + q write + diff. half 0 -> dims 0-31, half 1 -> dims 32-63.
  const float* __restrict__ er = et + (size_t)id * D;
  float* __restrict__ qr = q + (size_t)myq * D;
  float dacc = 0.f;
  if (half == 0) {
#pragma unroll
    for (int j = 0; j < 8; ++j) {
      const float4 ev = reinterpret_cast<const float4*>(er)[j];
      reinterpret_cast<float4*>(qr)[j] = ev;
      float dv;
      dv = ev.x - xv[4 * j + 0]; dacc = fmaf(dv, dv, dacc);
      dv = ev.y - xv[4 * j + 1]; dacc = fmaf(dv, dv, dacc);
      dv = ev.z - xv[4 * j + 2]; dacc = fmaf(dv, dv, dacc);
      dv = ev.w - xv[4 * j + 3]; dacc = fmaf(dv, dv, dacc);
    }
  } else {
#pragma unroll
    for (int j = 8; j < 16; ++j) {
      const float4 ev = reinterpret_cast<const float4*>(er)[j];
      reinterpret_cast<float4*>(qr)[j] = ev;
      float dv;
      dv = ev.x - xv[4 * j + 0]; dacc = fmaf(dv, dv, dacc);
      dv = ev.y - xv[4 * j + 1]; dacc = fmaf(dv, dv, dacc);
      dv = ev.z - xv[4 * j + 2]; dacc = fmaf(dv, dv, dacc);
      dv = ev.w - xv[4 * j + 3]; dacc = fmaf(dv, dv, dacc);
    }
  }
  // Deterministic wave + block reduction of diff partials.
  dacc += __shfl_down(dacc, 32, 64);
  dacc += __shfl_down(dacc, 16, 64);
  dacc += __shfl_down(dacc, 8, 64);
  dacc += __shfl_down(dacc, 4, 64);
  dacc += __shfl_down(dacc, 2, 64);
  dacc += __shfl_down(dacc, 1, 64);
  if (lane == 0) sd[wv] = dacc;
  __syncthreads();
  if (tid == 0)
    partial[blockIdx.x] = ((sd[0] + sd[1]) + (sd[2] + sd[3]));
}

// ---------------------------------------------------------------------------
// Finalize: sum the NBLK partials (fixed order) -> mean -> d_out scalar.
// ---------------------------------------------------------------------------
__global__ __launch_bounds__(256) void vq_finalize_kernel(
    const float* __restrict__ partial, float* __restrict__ out)
{
  float acc = 0.f;
  for (int i = threadIdx.x; i < NBLK; i += 256) acc += partial[i];
  acc += __shfl_down(acc, 32, 64);
  acc += __shfl_down(acc, 16, 64);
  acc += __shfl_down(acc, 8, 64);
  acc += __shfl_down(acc, 4, 64);
  acc += __shfl_down(acc, 2, 64);
  acc += __shfl_down(acc, 1, 64);
  __shared__ float sred[4];
  if ((threadIdx.x & 63) == 0) sred[threadIdx.x >> 6] = acc;
  __syncthreads();
  if (threadIdx.x == 0)
    out[0] = ((sred[0] + sred[1]) + (sred[2] + sred[3])) * (1.0f / (float)(N_VEC * D));
}

extern "C" void kernel_launch(void* const* d_in, const int* in_sizes, int n_in,
                              void* d_out, int out_size, void* d_ws, size_t ws_size,
                              hipStream_t stream) {
  const float* x = (const float*)d_in[0];
  const float* embed = (const float*)d_in[1];
  float* out = (float*)d_out;
  float* q    = out;                 // [0, 8388608): q_st
  float* diff = out + 8388608;       // [8388608]: commitment loss scalar
  float* idf  = out + 8388609;       // [8388609, +131072): emd_id as float
  float* et      = (float*)d_ws;            // [0, 32768): embed transposed [K][D]
  float* nrm     = (float*)d_ws + 32768;    // [32768, +512): code norms
  float* partial = (float*)d_ws + 33280;    // [33280, +1024): diff partials

  vq_prep_kernel<<<8, 64, 0, stream>>>(embed, et, nrm);
  vq_main_kernel<<<NBLK, 256, 0, stream>>>(x, et, nrm, q, idf, partial);
  vq_finalize_kernel<<<1, 256, 0, stream>>>(partial, diff);
}

// Round 5
// 226.939 us; speedup vs baseline: 2.5902x; 2.5902x over previous
//
#include <hip/hip_runtime.h>

// Problem constants: x [32,64,64,64] f32, embed [64,512] f32.
#define N_VEC 131072
#define D 64
#define K 512
#define GUARD 0.08f      // >= 6x worst-case coarse-score error bound (~1.2e-2)
#define NB_GATHER 2048

typedef __attribute__((ext_vector_type(8))) short bf16x8;  // 8 bf16 = 4 VGPR
typedef __attribute__((ext_vector_type(4))) float f32x4;

static __device__ __forceinline__ short f2bf(float f) {   // RNE, matches __float2bfloat16
  unsigned u = __builtin_bit_cast(unsigned, f);
  u += 0x7fffu + ((u >> 16) & 1u);
  return (short)(u >> 16);
}
static __device__ __forceinline__ float bf2f(short h) {
  unsigned u = ((unsigned)(unsigned short)h) << 16;
  return __builtin_bit_cast(float, u);
}

// ---------------------------------------------------------------------------
// Prep: et[k][d] fp32 transpose (exact copy), nrm (same fma order as rounds
// 1-3 -> bit-identical), and hi/mid bf16 splits ehT/emT [k][d].
// ---------------------------------------------------------------------------
__global__ __launch_bounds__(64) void vq_prep_kernel(
    const float* __restrict__ embed, float* __restrict__ et,
    float* __restrict__ nrm, short* __restrict__ ehT, short* __restrict__ emT)
{
  const int k = blockIdx.x * 64 + threadIdx.x;   // grid 8 x 64
  float s = 0.f;
#pragma unroll
  for (int d = 0; d < D; ++d) {
    const float e = embed[d * K + k];
    et[k * D + d] = e;
    const short h = f2bf(e);
    ehT[k * D + d] = h;
    emT[k * D + d] = f2bf(e - bf2f(h));
    s = fmaf(e, e, s);
  }
  nrm[k] = s;
}

// ---------------------------------------------------------------------------
// Coarse: wave = 16 queries (A-frags resident, bf16 hi/mid), stream 32 tiles
// of 16 codes; 6 MFMA per tile (hh+hm+mh over 2 K-chunks); track per-query
// best/2nd-best; flag gap<GUARD into bitmap; write provisional ids.
// mfma_f32_16x16x32_bf16: A(m,k): m=lane&15, k=(lane>>4)*8+j;
// B(k,n): n=lane&15, k=(lane>>4)*8+j; D(m,n): n=lane&15, m=(lane>>4)*4+reg.
// ---------------------------------------------------------------------------
__global__ __launch_bounds__(256) void vq_coarse_kernel(
    const float* __restrict__ x, const short* __restrict__ ehT,
    const short* __restrict__ emT, const float* __restrict__ nrm,
    float* __restrict__ idf, unsigned long long* __restrict__ bitmap)
{
  const int tid  = threadIdx.x;
  const int lane = tid & 63;
  const int wid  = blockIdx.x * 4 + (tid >> 6);
  const int qbase = wid * 16;
  const int row = lane & 15;
  const int kg  = lane >> 4;

  // Build A fragments (hi/mid) from x rows; per lane 8 consecutive dims.
  bf16x8 Ah[2], Am[2];
  {
    const float* xr = x + (size_t)(qbase + row) * D + kg * 8;
#pragma unroll
    for (int c = 0; c < 2; ++c) {
      const float4 f0 = *reinterpret_cast<const float4*>(xr + c * 32);
      const float4 f1 = *reinterpret_cast<const float4*>(xr + c * 32 + 4);
      const float v[8] = {f0.x, f0.y, f0.z, f0.w, f1.x, f1.y, f1.z, f1.w};
#pragma unroll
      for (int j = 0; j < 8; ++j) {
        const short h = f2bf(v[j]);
        Ah[c][j] = h;
        Am[c][j] = f2bf(v[j] - bf2f(h));
      }
    }
  }

  // B-frag per-lane base: code = tile*16 + row, dims kg*8.. ; strides in
  // bf16x8 units: tile = 16*64/8 = 128, chunk = 32/8 = 4.
  const bf16x8* pbh = reinterpret_cast<const bf16x8*>(ehT + row * D + kg * 8);
  const bf16x8* pbm = reinterpret_cast<const bf16x8*>(emT + row * D + kg * 8);

  float b1[4], b2[4]; int i1[4];
#pragma unroll
  for (int r = 0; r < 4; ++r) { b1[r] = 3.4e38f; b2[r] = 3.4e38f; i1[r] = 0; }

  bf16x8 Bh0 = pbh[0], Bh1 = pbh[4], Bm0 = pbm[0], Bm1 = pbm[4];

#pragma unroll 1
  for (int t = 0; t < 32; ++t) {
    const int tn = (t + 1) & 31;          // wraparound prefetch (branch-free)
    const bf16x8 nBh0 = pbh[tn * 128];
    const bf16x8 nBh1 = pbh[tn * 128 + 4];
    const bf16x8 nBm0 = pbm[tn * 128];
    const bf16x8 nBm1 = pbm[tn * 128 + 4];

    f32x4 accA = {0.f, 0.f, 0.f, 0.f}, accB = {0.f, 0.f, 0.f, 0.f};
    accA = __builtin_amdgcn_mfma_f32_16x16x32_bf16(Ah[0], Bh0, accA, 0, 0, 0);
    accB = __builtin_amdgcn_mfma_f32_16x16x32_bf16(Ah[1], Bh1, accB, 0, 0, 0);
    accA = __builtin_amdgcn_mfma_f32_16x16x32_bf16(Ah[0], Bm0, accA, 0, 0, 0);
    accB = __builtin_amdgcn_mfma_f32_16x16x32_bf16(Ah[1], Bm1, accB, 0, 0, 0);
    accA = __builtin_amdgcn_mfma_f32_16x16x32_bf16(Am[0], Bh0, accA, 0, 0, 0);
    accB = __builtin_amdgcn_mfma_f32_16x16x32_bf16(Am[1], Bh1, accB, 0, 0, 0);

    const float nv = nrm[t * 16 + row];   // this lane's code = D's col = row
    const int code = t * 16 + row;
#pragma unroll
    for (int r = 0; r < 4; ++r) {
      const float s = fmaf(-2.f, accA[r] + accB[r], nv);
      if (s < b1[r]) { b2[r] = b1[r]; b1[r] = s; i1[r] = code; }
      else if (s < b2[r]) { b2[r] = s; }
    }
    Bh0 = nBh0; Bh1 = nBh1; Bm0 = nBm0; Bm1 = nBm1;
  }

  // Butterfly merge of (b1,i1,b2) across the 16 lanes of each row-group
  // (disjoint code subsets -> exact 1st/2nd of the union).
#pragma unroll
  for (int m = 1; m < 16; m <<= 1) {
#pragma unroll
    for (int r = 0; r < 4; ++r) {
      const float o1 = __shfl_xor(b1[r], m, 64);
      const int   oi = __shfl_xor(i1[r], m, 64);
      const float o2 = __shfl_xor(b2[r], m, 64);
      if (o1 < b1[r]) { b2[r] = fminf(b1[r], o2); b1[r] = o1; i1[r] = oi; }
      else            { b2[r] = fminf(b2[r], o1); }   // ties land here -> gap 0 -> flagged
    }
  }

  if (row == 0) {   // lanes 0,16,32,48: write 4 queries each
    unsigned long long mask = 0ull;
#pragma unroll
    for (int r = 0; r < 4; ++r) {
      const int q = qbase + kg * 4 + r;
      idf[q] = (float)i1[r];
      if (b2[r] - b1[r] < GUARD) mask |= 1ull << (q & 63);
    }
    if (mask) atomicOr(&bitmap[qbase >> 6], mask);  // qbase..+15 share one word
  }
}

// ---------------------------------------------------------------------------
// Fallback: exact fp32 rescore of flagged queries (round-1 semantics: fma
// chain d ascending, score=fmaf(-2,dot,nrm), strict <, index tie-break).
// Wave per query; deterministic result regardless of atomic order.
// ---------------------------------------------------------------------------
__global__ __launch_bounds__(256) void vq_fallback_kernel(
    const float* __restrict__ x, const float* __restrict__ et,
    const float* __restrict__ nrm, const unsigned long long* __restrict__ bitmap,
    float* __restrict__ idf)
{
  const int lane = threadIdx.x & 63;
  const int wid  = blockIdx.x * 4 + (threadIdx.x >> 6);
  const int nw   = gridDim.x * 4;
  for (int w = wid; w < N_VEC / 64; w += nw) {
    unsigned long long word = bitmap[w];
    while (word) {
      const int bit = __ffsll((long long)word) - 1;
      word &= word - 1;
      const int q = w * 64 + bit;
      float xv[D];
      {
        const float4* xr = reinterpret_cast<const float4*>(x + (size_t)q * D);
#pragma unroll
        for (int j = 0; j < D / 4; ++j) {
          const float4 t = xr[j];
          xv[4*j] = t.x; xv[4*j+1] = t.y; xv[4*j+2] = t.z; xv[4*j+3] = t.w;
        }
      }
      float best = 3.4e38f; int bid = 0;
#pragma unroll 1
      for (int g = 0; g < 8; ++g) {
        const int k = g * 64 + lane;
        const float* er = et + (size_t)k * D;
        float a = 0.f;
#pragma unroll
        for (int d = 0; d < D; ++d) a = fmaf(xv[d], er[d], a);
        const float s = fmaf(-2.f, a, nrm[k]);
        if (s < best) { best = s; bid = k; }
      }
#pragma unroll
      for (int off = 32; off > 0; off >>= 1) {
        const float s2 = __shfl_down(best, off, 64);
        const int   b2 = __shfl_down(bid, off, 64);
        if (s2 < best || (s2 == best && b2 < bid)) { best = s2; bid = b2; }
      }
      if (lane == 0) idf[q] = (float)bid;
    }
  }
}

// ---------------------------------------------------------------------------
// Gather: q = et[id] (exact fp32 codebook rows), write q_st, diff partials.
// ---------------------------------------------------------------------------
__global__ __launch_bounds__(256) void vq_gather_kernel(
    const float* __restrict__ x, const float* __restrict__ et,
    const float* __restrict__ idf, float* __restrict__ q,
    float* __restrict__ partial)
{
  const int tid = blockIdx.x * 256 + threadIdx.x;
  const int stride = gridDim.x * 256;
  float acc = 0.f;
  for (int idx = tid; idx < N_VEC * (D / 4); idx += stride) {
    const int v = idx >> 4;
    const int d4 = idx & 15;
    const int id = (int)idf[v];
    const float4 xv = reinterpret_cast<const float4*>(x)[idx];
    const float4 ev = reinterpret_cast<const float4*>(et)[(id << 4) + d4];
    const float e0 = ev.x - xv.x, e1 = ev.y - xv.y, e2 = ev.z - xv.z, e3 = ev.w - xv.w;
    acc += (e0 * e0 + e1 * e1) + (e2 * e2 + e3 * e3);
    reinterpret_cast<float4*>(q)[idx] = ev;
  }
  acc += __shfl_down(acc, 32, 64);
  acc += __shfl_down(acc, 16, 64);
  acc += __shfl_down(acc, 8, 64);
  acc += __shfl_down(acc, 4, 64);
  acc += __shfl_down(acc, 2, 64);
  acc += __shfl_down(acc, 1, 64);
  __shared__ float sred[4];
  if ((threadIdx.x & 63) == 0) sred[threadIdx.x >> 6] = acc;
  __syncthreads();
  if (threadIdx.x == 0)
    partial[blockIdx.x] = (sred[0] + sred[1]) + (sred[2] + sred[3]);
}

__global__ __launch_bounds__(256) void vq_finalize_kernel(
    const float* __restrict__ partial, float* __restrict__ out)
{
  float acc = 0.f;
  for (int i = threadIdx.x; i < NB_GATHER; i += 256) acc += partial[i];
  acc += __shfl_down(acc, 32, 64);
  acc += __shfl_down(acc, 16, 64);
  acc += __shfl_down(acc, 8, 64);
  acc += __shfl_down(acc, 4, 64);
  acc += __shfl_down(acc, 2, 64);
  acc += __shfl_down(acc, 1, 64);
  __shared__ float sred[4];
  if ((threadIdx.x & 63) == 0) sred[threadIdx.x >> 6] = acc;
  __syncthreads();
  if (threadIdx.x == 0)
    out[0] = ((sred[0] + sred[1]) + (sred[2] + sred[3])) * (1.0f / (float)(N_VEC * D));
}

extern "C" void kernel_launch(void* const* d_in, const int* in_sizes, int n_in,
                              void* d_out, int out_size, void* d_ws, size_t ws_size,
                              hipStream_t stream) {
  const float* x = (const float*)d_in[0];
  const float* embed = (const float*)d_in[1];
  float* out = (float*)d_out;
  float* q    = out;                 // [0, 8388608): q_st
  float* diff = out + 8388608;       // commitment loss scalar
  float* idf  = out + 8388609;       // emd_id as float [131072]

  float* ws = (float*)d_ws;          // layout (float idx), ~290 KB total:
  float* et      = ws;               // [0, 32768)      fp32 codebook rows
  float* nrm     = ws + 32768;       // [32768, 33280)  code norms
  float* partial = ws + 33280;       // [33280, 35328)  diff partials
  unsigned long long* bitmap = (unsigned long long*)(ws + 35328);  // 16 KB
  short* ehT = (short*)(ws + 39424); // 64 KB bf16-hi codebook
  short* emT = (short*)(ws + 55808); // 64 KB bf16-mid codebook

  hipMemsetAsync(bitmap, 0, 2048 * sizeof(unsigned long long), stream);
  vq_prep_kernel<<<8, 64, 0, stream>>>(embed, et, nrm, ehT, emT);
  vq_coarse_kernel<<<2048, 256, 0, stream>>>(x, ehT, emT, nrm, idf, bitmap);
  vq_fallback_kernel<<<256, 256, 0, stream>>>(x, et, nrm, bitmap, idf);
  vq_gather_kernel<<<NB_GATHER, 256, 0, stream>>>(x, et, idf, q, partial);
  vq_finalize_kernel<<<1, 256, 0, stream>>>(partial, diff);
}

// Round 6
// 137.532 us; speedup vs baseline: 4.2741x; 1.6501x over previous
//
#include <hip/hip_runtime.h>

// Problem constants: x [32,64,64,64] f32, embed [64,512] f32.
#define N_VEC 131072
#define D 64
#define K 512
#define GUARD 0.08f      // >= 6x worst-case coarse-score error bound (~1.2e-2)
#define NB_GATHER 2048

typedef __attribute__((ext_vector_type(8))) short bf16x8;  // 8 bf16 = 4 VGPR
typedef __attribute__((ext_vector_type(4))) float f32x4;

static __device__ __forceinline__ short f2bf(float f) {   // RNE
  unsigned u = __builtin_bit_cast(unsigned, f);
  u += 0x7fffu + ((u >> 16) & 1u);
  return (short)(u >> 16);
}
static __device__ __forceinline__ float bf2f(short h) {
  unsigned u = ((unsigned)(unsigned short)h) << 16;
  return __builtin_bit_cast(float, u);
}
static __device__ __forceinline__ void split8(const float4 f0, const float4 f1,
                                              bf16x8& h, bf16x8& m) {
  const float v[8] = {f0.x, f0.y, f0.z, f0.w, f1.x, f1.y, f1.z, f1.w};
#pragma unroll
  for (int j = 0; j < 8; ++j) {
    const short hh = f2bf(v[j]);
    h[j] = hh;
    m[j] = f2bf(v[j] - bf2f(hh));
  }
}

// ---------------------------------------------------------------------------
// Prep (grid 40 x 64):
//   blocks 0-31:  pack codebook hi/mid bf16 B-fragments for tile b into F,
//                 in exact MFMA fragment order: F[t*256 + c*128 + s*64 + lane]
//                 (bf16x8 units; c = K-chunk, s = 0 hi / 1 mid), so a wave's
//                 B load is one contiguous 1-KB read.
//   blocks 32-39: et[k][d] fp32 transpose + nrm (fma order d ascending, same
//                 as rounds 1-5 -> bit-identical) + bitmap zeroing.
// ---------------------------------------------------------------------------
__global__ __launch_bounds__(64) void vq_prep_kernel(
    const float* __restrict__ embed, float* __restrict__ et,
    float* __restrict__ nrm, bf16x8* __restrict__ F,
    unsigned long long* __restrict__ bitmap)
{
  const int b = blockIdx.x;
  const int lane = threadIdx.x;
  if (b < 32) {
    const int row = lane & 15;   // code within tile
    const int kg  = lane >> 4;   // dim-group
    const int code = b * 16 + row;
#pragma unroll
    for (int c = 0; c < 2; ++c) {
      bf16x8 h, m;
#pragma unroll
      for (int j = 0; j < 8; ++j) {
        const int d = kg * 8 + c * 32 + j;
        const float e = embed[d * K + code];
        const short hh = f2bf(e);
        h[j] = hh;
        m[j] = f2bf(e - bf2f(hh));
      }
      F[b * 256 + c * 128 + 0  + lane] = h;
      F[b * 256 + c * 128 + 64 + lane] = m;
    }
  } else {
    const int t512 = (b - 32) * 64 + lane;     // 0..511
    const int code = t512;
    float s = 0.f;
#pragma unroll
    for (int d = 0; d < D; ++d) {
      const float e = embed[d * K + code];
      et[code * D + d] = e;
      s = fmaf(e, e, s);
    }
    nrm[code] = s;
#pragma unroll
    for (int i = 0; i < 4; ++i) bitmap[t512 + i * 512] = 0ull;
  }
}

// ---------------------------------------------------------------------------
// Coarse: wave = 32 queries (two 16-row A-sets, hi/mid bf16), streams 32
// code-tiles of 16 via pre-packed B-frags (coalesced 1KB loads, one tile
// prefetch). 12 MFMA/tile (hh+hm+mh over 2 K-chunks x 2 A-sets). Per lane:
// 8 (query) best/2nd/idx triples. gap<GUARD -> bitmap for exact fallback.
// Verified fragment maps (round 5 passed): A(m,k): m=lane&15,
// k=(lane>>4)*8+c*32+j; B(k,n): n=lane&15, k same; D(m,n): n=lane&15,
// m=(lane>>4)*4+r.
// ---------------------------------------------------------------------------
__global__ __launch_bounds__(256, 4) void vq_coarse_kernel(
    const float* __restrict__ x, const bf16x8* __restrict__ F,
    const float* __restrict__ nrm, float* __restrict__ idf,
    unsigned long long* __restrict__ bitmap)
{
  const int tid  = threadIdx.x;
  const int lane = tid & 63;
  const int wid  = blockIdx.x * 4 + (tid >> 6);
  const int qbase = wid * 32;
  const int row = lane & 15;
  const int kg  = lane >> 4;

  // Build A fragments (2 query-sets x 2 K-chunks, hi+mid).
  bf16x8 Ah0c0, Ah0c1, Ah1c0, Ah1c1, Am0c0, Am0c1, Am1c0, Am1c1;
  {
    const float* xr0 = x + (size_t)(qbase + row) * D + kg * 8;
    const float* xr1 = x + (size_t)(qbase + 16 + row) * D + kg * 8;
    split8(*reinterpret_cast<const float4*>(xr0),
           *reinterpret_cast<const float4*>(xr0 + 4), Ah0c0, Am0c0);
    split8(*reinterpret_cast<const float4*>(xr0 + 32),
           *reinterpret_cast<const float4*>(xr0 + 36), Ah0c1, Am0c1);
    split8(*reinterpret_cast<const float4*>(xr1),
           *reinterpret_cast<const float4*>(xr1 + 4), Ah1c0, Am1c0);
    split8(*reinterpret_cast<const float4*>(xr1 + 32),
           *reinterpret_cast<const float4*>(xr1 + 36), Ah1c1, Am1c1);
  }

  float b1[8], b2[8]; int i1[8];   // [s*4+r]
#pragma unroll
  for (int r = 0; r < 8; ++r) { b1[r] = 3.4e38f; b2[r] = 3.4e38f; i1[r] = 0; }

  // Preload tile 0 B-frags + norm.
  bf16x8 Bh0 = F[lane], Bm0 = F[64 + lane], Bh1 = F[128 + lane], Bm1 = F[192 + lane];
  float nv = nrm[row];

#pragma unroll 1
  for (int t = 0; t < 32; ++t) {
    const int tn = (t + 1) & 31;                 // wraparound prefetch
    const bf16x8 nBh0 = F[tn * 256 + lane];
    const bf16x8 nBm0 = F[tn * 256 + 64 + lane];
    const bf16x8 nBh1 = F[tn * 256 + 128 + lane];
    const bf16x8 nBm1 = F[tn * 256 + 192 + lane];
    const float nvn = nrm[tn * 16 + row];

    f32x4 a0 = {0.f, 0.f, 0.f, 0.f}, a1 = {0.f, 0.f, 0.f, 0.f};
    a0 = __builtin_amdgcn_mfma_f32_16x16x32_bf16(Ah0c0, Bh0, a0, 0, 0, 0);
    a1 = __builtin_amdgcn_mfma_f32_16x16x32_bf16(Ah1c0, Bh0, a1, 0, 0, 0);
    a0 = __builtin_amdgcn_mfma_f32_16x16x32_bf16(Ah0c1, Bh1, a0, 0, 0, 0);
    a1 = __builtin_amdgcn_mfma_f32_16x16x32_bf16(Ah1c1, Bh1, a1, 0, 0, 0);
    a0 = __builtin_amdgcn_mfma_f32_16x16x32_bf16(Ah0c0, Bm0, a0, 0, 0, 0);
    a1 = __builtin_amdgcn_mfma_f32_16x16x32_bf16(Ah1c0, Bm0, a1, 0, 0, 0);
    a0 = __builtin_amdgcn_mfma_f32_16x16x32_bf16(Ah0c1, Bm1, a0, 0, 0, 0);
    a1 = __builtin_amdgcn_mfma_f32_16x16x32_bf16(Ah1c1, Bm1, a1, 0, 0, 0);
    a0 = __builtin_amdgcn_mfma_f32_16x16x32_bf16(Am0c0, Bh0, a0, 0, 0, 0);
    a1 = __builtin_amdgcn_mfma_f32_16x16x32_bf16(Am1c0, Bh0, a1, 0, 0, 0);
    a0 = __builtin_amdgcn_mfma_f32_16x16x32_bf16(Am0c1, Bh1, a0, 0, 0, 0);
    a1 = __builtin_amdgcn_mfma_f32_16x16x32_bf16(Am1c1, Bh1, a1, 0, 0, 0);

    const int code = t * 16 + row;
#pragma unroll
    for (int r = 0; r < 4; ++r) {
      const float s0 = fmaf(-2.f, a0[r], nv);
      b2[r] = fminf(b2[r], fmaxf(b1[r], s0));
      if (s0 < b1[r]) { b1[r] = s0; i1[r] = code; }
      const float s1 = fmaf(-2.f, a1[r], nv);
      b2[4 + r] = fminf(b2[4 + r], fmaxf(b1[4 + r], s1));
      if (s1 < b1[4 + r]) { b1[4 + r] = s1; i1[4 + r] = code; }
    }
    Bh0 = nBh0; Bm0 = nBm0; Bh1 = nBh1; Bm1 = nBm1; nv = nvn;
  }

  // Butterfly merge across the 16 rows of each quarter-wave (disjoint code
  // subsets -> exact 1st/2nd of union; ties -> gap 0 -> flagged).
#pragma unroll
  for (int m = 1; m < 16; m <<= 1) {
#pragma unroll
    for (int r = 0; r < 8; ++r) {
      const float o1 = __shfl_xor(b1[r], m, 64);
      const int   oi = __shfl_xor(i1[r], m, 64);
      const float o2 = __shfl_xor(b2[r], m, 64);
      if (o1 < b1[r]) { b2[r] = fminf(b1[r], o2); b1[r] = o1; i1[r] = oi; }
      else            { b2[r] = fminf(b2[r], o1); }
    }
  }

  if (row == 0) {   // lanes 0,16,32,48: each owns 8 queries (2 sets x 4 regs)
    unsigned long long mask = 0ull;
#pragma unroll
    for (int r = 0; r < 8; ++r) {
      const int q = qbase + (r >> 2) * 16 + kg * 4 + (r & 3);
      idf[q] = (float)i1[r];
      if (b2[r] - b1[r] < GUARD) mask |= 1ull << (q & 63);
    }
    if (mask) atomicOr(&bitmap[qbase >> 6], mask);
  }
}

// ---------------------------------------------------------------------------
// Fallback: exact fp32 rescore of flagged queries (round-1 semantics: fma
// chain d ascending, score=fmaf(-2,dot,nrm), strict <, index tie-break).
// ---------------------------------------------------------------------------
__global__ __launch_bounds__(256) void vq_fallback_kernel(
    const float* __restrict__ x, const float* __restrict__ et,
    const float* __restrict__ nrm, const unsigned long long* __restrict__ bitmap,
    float* __restrict__ idf)
{
  const int lane = threadIdx.x & 63;
  const int wid  = blockIdx.x * 4 + (threadIdx.x >> 6);
  const int nw   = gridDim.x * 4;
  for (int w = wid; w < N_VEC / 64; w += nw) {
    unsigned long long word = bitmap[w];
    while (word) {
      const int bit = __ffsll((long long)word) - 1;
      word &= word - 1;
      const int q = w * 64 + bit;
      float xv[D];
      {
        const float4* xr = reinterpret_cast<const float4*>(x + (size_t)q * D);
#pragma unroll
        for (int j = 0; j < D / 4; ++j) {
          const float4 t = xr[j];
          xv[4*j] = t.x; xv[4*j+1] = t.y; xv[4*j+2] = t.z; xv[4*j+3] = t.w;
        }
      }
      float best = 3.4e38f; int bid = 0;
#pragma unroll 1
      for (int g = 0; g < 8; ++g) {
        const int k = g * 64 + lane;
        const float* er = et + (size_t)k * D;
        float a = 0.f;
#pragma unroll
        for (int d = 0; d < D; ++d) a = fmaf(xv[d], er[d], a);
        const float s = fmaf(-2.f, a, nrm[k]);
        if (s < best) { best = s; bid = k; }
      }
#pragma unroll
      for (int off = 32; off > 0; off >>= 1) {
        const float s2 = __shfl_down(best, off, 64);
        const int   b2 = __shfl_down(bid, off, 64);
        if (s2 < best || (s2 == best && b2 < bid)) { best = s2; bid = b2; }
      }
      if (lane == 0) idf[q] = (float)bid;
    }
  }
}

// ---------------------------------------------------------------------------
// Gather: q = et[id] (exact fp32 rows), write q_st, diff partials.
// ---------------------------------------------------------------------------
__global__ __launch_bounds__(256) void vq_gather_kernel(
    const float* __restrict__ x, const float* __restrict__ et,
    const float* __restrict__ idf, float* __restrict__ q,
    float* __restrict__ partial)
{
  const int tid = blockIdx.x * 256 + threadIdx.x;
  const int stride = gridDim.x * 256;
  float acc = 0.f;
  for (int idx = tid; idx < N_VEC * (D / 4); idx += stride) {
    const int v = idx >> 4;
    const int d4 = idx & 15;
    const int id = (int)idf[v];
    const float4 xv = reinterpret_cast<const float4*>(x)[idx];
    const float4 ev = reinterpret_cast<const float4*>(et)[(id << 4) + d4];
    const float e0 = ev.x - xv.x, e1 = ev.y - xv.y, e2 = ev.z - xv.z, e3 = ev.w - xv.w;
    acc += (e0 * e0 + e1 * e1) + (e2 * e2 + e3 * e3);
    reinterpret_cast<float4*>(q)[idx] = ev;
  }
  acc += __shfl_down(acc, 32, 64);
  acc += __shfl_down(acc, 16, 64);
  acc += __shfl_down(acc, 8, 64);
  acc += __shfl_down(acc, 4, 64);
  acc += __shfl_down(acc, 2, 64);
  acc += __shfl_down(acc, 1, 64);
  __shared__ float sred[4];
  if ((threadIdx.x & 63) == 0) sred[threadIdx.x >> 6] = acc;
  __syncthreads();
  if (threadIdx.x == 0)
    partial[blockIdx.x] = (sred[0] + sred[1]) + (sred[2] + sred[3]);
}

__global__ __launch_bounds__(256) void vq_finalize_kernel(
    const float* __restrict__ partial, float* __restrict__ out)
{
  float acc = 0.f;
  for (int i = threadIdx.x; i < NB_GATHER; i += 256) acc += partial[i];
  acc += __shfl_down(acc, 32, 64);
  acc += __shfl_down(acc, 16, 64);
  acc += __shfl_down(acc, 8, 64);
  acc += __shfl_down(acc, 4, 64);
  acc += __shfl_down(acc, 2, 64);
  acc += __shfl_down(acc, 1, 64);
  __shared__ float sred[4];
  if ((threadIdx.x & 63) == 0) sred[threadIdx.x >> 6] = acc;
  __syncthreads();
  if (threadIdx.x == 0)
    out[0] = ((sred[0] + sred[1]) + (sred[2] + sred[3])) * (1.0f / (float)(N_VEC * D));
}

extern "C" void kernel_launch(void* const* d_in, const int* in_sizes, int n_in,
                              void* d_out, int out_size, void* d_ws, size_t ws_size,
                              hipStream_t stream) {
  const float* x = (const float*)d_in[0];
  const float* embed = (const float*)d_in[1];
  float* out = (float*)d_out;
  float* q    = out;                 // [0, 8388608): q_st
  float* diff = out + 8388608;       // commitment loss scalar
  float* idf  = out + 8388609;       // emd_id as float [131072]

  float* ws = (float*)d_ws;          // layout (float idx):
  float* et      = ws;               // [0, 32768)      fp32 codebook rows, 128 KB
  float* nrm     = ws + 32768;       // [32768, 33280)  code norms
  float* partial = ws + 33280;       // [33280, 35328)  diff partials
  unsigned long long* bitmap = (unsigned long long*)(ws + 35328);  // 16 KB
  bf16x8* F = (bf16x8*)(ws + 39424); // 128 KB packed hi/mid B-fragments

  vq_prep_kernel<<<40, 64, 0, stream>>>(embed, et, nrm, F, bitmap);
  vq_coarse_kernel<<<N_VEC / 128, 256, 0, stream>>>(x, F, nrm, idf, bitmap);
  vq_fallback_kernel<<<256, 256, 0, stream>>>(x, et, nrm, bitmap, idf);
  vq_gather_kernel<<<NB_GATHER, 256, 0, stream>>>(x, et, idf, q, partial);
  vq_finalize_kernel<<<1, 256, 0, stream>>>(partial, diff);
}